// Round 13
// baseline (214.019 us; speedup 1.0000x reference)
//
#include <hip/hip_runtime.h>

// MultiheadAttentionWithBias: B=2, L=2048, D=1024, H=16, HD=64
// R13: attn restructured so ALL global reads are large sequential runs staged
// through LDS (bias f32 panels + K + V^T, dbuf, 128KB LDS), consumers read
// LDS only. Block = 2 q-strips x 4 k-quarters (fixed-max k-split, in-block
// combine). Tests the request-granularity theory from R10/R12 counters.

typedef __attribute__((ext_vector_type(8))) short bf16x8;
typedef __attribute__((ext_vector_type(4))) float f32x4;
typedef __attribute__((ext_vector_type(16))) float f32x16;
typedef __attribute__((ext_vector_type(8))) unsigned short u16x8;
using u16 = unsigned short;

#define MFMA16(a, b, c) __builtin_amdgcn_mfma_f32_16x16x32_bf16((a), (b), (c), 0, 0, 0)
#define MFMA32(a, b, c) __builtin_amdgcn_mfma_f32_32x32x16_bf16((a), (b), (c), 0, 0, 0)
#define LOG2E 1.44269504088896f
#define QSCALE (0.125f * 1.44269504088896f)

__device__ __forceinline__ u16 f2bf(float f) {
  union { float f; unsigned int u; } v; v.f = f;
  unsigned int r = v.u + 0x7FFFu + ((v.u >> 16) & 1u);
  return (u16)(r >> 16);
}

__device__ __forceinline__ unsigned cvt_pk_bf16(float lo, float hi) {
  unsigned r;
  asm volatile("v_cvt_pk_bf16_f32 %0, %1, %2" : "=v"(r) : "v"(lo), "v"(hi));
  return r;
}

__device__ __forceinline__ void pl32swap(unsigned& a, unsigned& b) {
#if __has_builtin(__builtin_amdgcn_permlane32_swap)
  typedef unsigned pl2 __attribute__((ext_vector_type(2)));
  pl2 r = __builtin_amdgcn_permlane32_swap(a, b, false, false);
  a = r[0];
  b = r[1];
#else
  asm volatile("v_permlane32_swap_b32 %0, %1" : "+v"(a), "+v"(b));
#endif
}

__device__ __forceinline__ void g2lds16(const void* gsrc, void* ldst) {
  __builtin_amdgcn_global_load_lds(
      (const __attribute__((address_space(1))) unsigned int*)gsrc,
      (__attribute__((address_space(3))) unsigned int*)ldst, 16, 0, 0);
}

// ---------------- merged f32 -> bf16 convert (x, Wq, Wk, Wv, Wo) ----------------
__global__ __launch_bounds__(256) void cvt_all(
    const float* __restrict__ x, const float* __restrict__ wq,
    const float* __restrict__ wk, const float* __restrict__ wv,
    const float* __restrict__ wo, u16* __restrict__ xb,
    u16* __restrict__ w1b, u16* __restrict__ wob) {
  int bid = blockIdx.x, tid = threadIdx.x;
  const float* src; u16* dst; int i;
  if (bid < 2048)      { src = x;  dst = xb;            i = bid * 256 + tid; }
  else if (bid < 2560) { src = wq; dst = w1b;           i = (bid - 2048) * 256 + tid; }
  else if (bid < 3072) { src = wk; dst = w1b + (1<<20); i = (bid - 2560) * 256 + tid; }
  else if (bid < 3584) { src = wv; dst = w1b + (2<<20); i = (bid - 3072) * 256 + tid; }
  else                 { src = wo; dst = wob;           i = (bid - 3584) * 256 + tid; }
  const float4* s = (const float4*)src;
  float4 a = s[2 * i], b = s[2 * i + 1];
  u16x8 o;
  o[0] = f2bf(a.x); o[1] = f2bf(a.y); o[2] = f2bf(a.z); o[3] = f2bf(a.w);
  o[4] = f2bf(b.x); o[5] = f2bf(b.y); o[6] = f2bf(b.z); o[7] = f2bf(b.w);
  ((u16x8*)dst)[i] = o;
}

// ---------------- GEMM C = A * B^T (unchanged, passing) ----------------
template <int MODE>
__global__ __launch_bounds__(256, 2) void gemm_bt(
    const u16* __restrict__ A, const u16* __restrict__ B,
    u16* __restrict__ qp, u16* __restrict__ kp, u16* __restrict__ vp,
    const float* __restrict__ b0, const float* __restrict__ b1,
    const float* __restrict__ b2, float* __restrict__ outp,
    const float* __restrict__ bo) {
  __shared__ __align__(16) u16 lA[128 * 64];
  __shared__ __align__(16) u16 lB[128 * 64];
  const int tid = threadIdx.x;
  const int lane = tid & 63, wid = tid >> 6;
  const int g = lane >> 4, cc = lane & 15;
  const int wr = wid >> 1, wc = wid & 1;
  const int m0 = blockIdx.y * 128, n0 = blockIdx.x * 128;
  f32x4 acc[4][4] = {};
  for (int kt = 0; kt < 16; ++kt) {
    const int kof = kt * 64;
#pragma unroll
    for (int i = 0; i < 4; ++i) {
      int cid = i * 256 + tid;
      int row = cid >> 3;
      int col = (cid & 7) * 8;
      g2lds16(A + (size_t)(m0 + row) * 1024 + kof + col, &lA[(i * 256 + wid * 64) * 8]);
      g2lds16(B + (size_t)(n0 + row) * 1024 + kof + col, &lB[(i * 256 + wid * 64) * 8]);
    }
    __syncthreads();
#pragma unroll
    for (int kc = 0; kc < 2; ++kc) {
      bf16x8 af[4], bfr[4];
#pragma unroll
      for (int mf = 0; mf < 4; ++mf)
        af[mf] = *(const bf16x8*)&lA[(wr * 64 + mf * 16 + cc) * 64 + kc * 32 + g * 8];
#pragma unroll
      for (int nf = 0; nf < 4; ++nf)
        bfr[nf] = *(const bf16x8*)&lB[(wc * 64 + nf * 16 + cc) * 64 + kc * 32 + g * 8];
#pragma unroll
      for (int mf = 0; mf < 4; ++mf)
#pragma unroll
        for (int nf = 0; nf < 4; ++nf)
          acc[mf][nf] = MFMA16(af[mf], bfr[nf], acc[mf][nf]);
    }
    __syncthreads();
  }
#pragma unroll
  for (int mf = 0; mf < 4; ++mf) {
#pragma unroll
    for (int nf = 0; nf < 4; ++nf) {
      int n = n0 + wc * 64 + nf * 16 + cc;
      if (MODE == 0) {
        int which = n >> 10;
        int nn = n & 1023;
        const float* bp = which == 0 ? b0 : (which == 1 ? b1 : b2);
        float bias = bp[nn];
        int h = nn >> 6, hd = nn & 63;
        int mb = m0 + wr * 64 + mf * 16 + g * 4;
        int bb = mb >> 11, ll0 = mb & 2047;
        if (which == 2) {
          ushort4 pk4;
          pk4.x = f2bf(acc[mf][nf][0] + bias);
          pk4.y = f2bf(acc[mf][nf][1] + bias);
          pk4.z = f2bf(acc[mf][nf][2] + bias);
          pk4.w = f2bf(acc[mf][nf][3] + bias);
          *(ushort4*)&vp[(((size_t)(bb * 16 + h)) * 64 + hd) * 2048 + ll0] = pk4;
        } else {
          u16* dp = which == 0 ? qp : kp;
#pragma unroll
          for (int r = 0; r < 4; ++r) {
            float val = acc[mf][nf][r] + bias;
            if (which == 0) val *= QSCALE;
            dp[(((size_t)(bb * 16 + h)) * 2048 + ll0 + r) * 64 + hd] = f2bf(val);
          }
        }
      } else {
        float bias = bo[n];
#pragma unroll
        for (int r = 0; r < 4; ++r) {
          int m = m0 + wr * 64 + mf * 16 + g * 4 + r;
          outp[(size_t)m * 1024 + n] = acc[mf][nf][r] + bias;
        }
      }
    }
  }
}

// ---------------- Flash attention: LDS-staged bias, sequential global reads ----
// Grid 1024 = 2b x 16h x 32 qstrips(64 rows). Block 512 thr = 8 waves =
// 2 q-strips(32 rows) x 4 k-quarters(32 k each). 16 half-panels of 128 k.
// Per half-panel, the block stages (all reads CONTIGUOUS >=128B runs, g2lds):
//   bias f32 64q x 128k (32KB), K 128k x 64d bf16 (16KB), V^T 64d x 128k (16KB)
// double-buffered (128KB LDS). Consumers read LDS only (XOR-swizzled via
// pre-swizzled global source). Fixed-max (-32) softmax -> 4-way k-split
// partials add exactly; in-block LDS combine at the end.
__global__ __launch_bounds__(512, 1) void attn_kernel(
    const u16* __restrict__ qm, const u16* __restrict__ km,
    const u16* __restrict__ vtm, const float* __restrict__ bias,
    u16* __restrict__ aout) {
  __shared__ __align__(16) unsigned char smem[131072];
  // layout: bias[2] @0 (2x32KB), K[2] @65536 (2x16KB), V[2] @98304 (2x16KB)
  const int tid = threadIdx.x;
  const int lane = tid & 63, wid = tid >> 6;
  const int lq = lane & 31, hi = lane >> 5;
  const int s = wid & 1, kq = wid >> 1;  // q-strip, k-quarter
  // XCD swizzle: 1024 blocks; xcd = lin&7 owns heads 2*xcd, 2*xcd+1
  const int lin = blockIdx.x;
  const int xcd = lin & 7, j = lin >> 3;   // j in [0,128)
  const int h = xcd * 2 + (j >> 6);
  const int rem = j & 63;
  const int b = rem >> 5, qs = rem & 31;
  const int q0 = qs * 64;
  const size_t bh = (size_t)b * 16 + h;
  const u16* kg = km + bh * 2048 * 64;
  const u16* vg = vtm + bh * 64 * 2048;
  const float* bg = bias + (size_t)h * 2048 * 2048;
  const u16* qbase = qm + (bh * 2048 + q0 + s * 32) * 64;

  // Q fragments (B-operand), constant: Q[q=lq][d=i*16+8hi..]
  bf16x8 qf[4];
#pragma unroll
  for (int i = 0; i < 4; ++i)
    qf[i] = *(const bf16x8*)&qbase[(size_t)lq * 64 + i * 16 + 8 * hi];

  f32x16 o[2];
#pragma unroll
  for (int r = 0; r < 16; ++r) { o[0][r] = 0.f; o[1][r] = 0.f; }
  float lsum = 0.f;

  // stage one 128-k half-panel into buf P. All global reads are contiguous
  // runs (bias 512B/row, K 128B/row, V 256B/row), XOR-swizzle pre-applied
  // on the SOURCE so linear g2lds dest yields swizzled LDS (T2 both-sides).
#define STAGE_HP(P, k0n)                                                       \
  {                                                                            \
    unsigned char* bdst = smem + (P) * 32768;                                  \
    unsigned char* kdst = smem + 65536 + (P) * 16384;                          \
    unsigned char* vdst = smem + 98304 + (P) * 16384;                          \
    _Pragma("unroll") for (int i = 0; i < 4; ++i) {                            \
      int slot = i * 512 + tid;                                                \
      int row = slot >> 5, cl = slot & 31;                                     \
      g2lds16(bg + (size_t)(q0 + row) * 2048 + (k0n) + ((cl ^ (row & 31)) << 2), \
              bdst + slot * 16);                                               \
    }                                                                          \
    _Pragma("unroll") for (int i = 0; i < 2; ++i) {                            \
      int slot = i * 512 + tid;                                                \
      int kr = slot >> 3, cl = slot & 7;                                       \
      g2lds16(kg + (size_t)((k0n) + kr) * 64 + ((cl ^ (kr & 7)) << 3),         \
              kdst + slot * 16);                                               \
    }                                                                          \
    _Pragma("unroll") for (int i = 0; i < 2; ++i) {                            \
      int slot = i * 512 + tid;                                                \
      int d = slot >> 4, cl = slot & 15;                                       \
      g2lds16(vg + (size_t)d * 2048 + (k0n) + ((cl ^ (d & 15)) << 3),          \
              vdst + slot * 16);                                               \
    }                                                                          \
  }

  // prologue: stage half-panel 0 -> buf0
  STAGE_HP(0, 0)
  __builtin_amdgcn_sched_barrier(0);
  asm volatile("s_waitcnt vmcnt(0)" ::: "memory");
  __builtin_amdgcn_sched_barrier(0);
  __builtin_amdgcn_s_barrier();
  __builtin_amdgcn_sched_barrier(0);

#pragma unroll 1
  for (int hp = 0; hp < 16; ++hp) {
    const int P = hp & 1;
    if (hp < 15) { STAGE_HP(P ^ 1, (hp + 1) * 128) }
    __builtin_amdgcn_sched_barrier(0);
    // ---- compute on buf P: one 32-k subtile (this wave's quarter) ----
    const u16* lK = (const u16*)(smem + 65536 + P * 16384);
    const u16* lV = (const u16*)(smem + 98304 + P * 16384);
    const float4* lB = (const float4*)(smem + P * 32768);
    f32x16 acc;
#pragma unroll
    for (int r = 0; r < 16; ++r) acc[r] = -32.0f;  // fixed-max fold
    const int krow = kq * 32 + lq;
#pragma unroll
    for (int i = 0; i < 4; ++i) {
      bf16x8 kf = *(const bf16x8*)&lK[krow * 64 + (((2 * i + hi) ^ (krow & 7))) * 8];
      acc = MFMA32(kf, qf[i], acc);
    }
    const int brow = s * 32 + lq;
#pragma unroll
    for (int g = 0; g < 4; ++g) {
      float4 b4 = lB[brow * 32 + ((kq * 8 + 2 * g + hi) ^ (brow & 31))];
      acc[g * 4 + 0] = fmaf(b4.x, LOG2E, acc[g * 4 + 0]);
      acc[g * 4 + 1] = fmaf(b4.y, LOG2E, acc[g * 4 + 1]);
      acc[g * 4 + 2] = fmaf(b4.z, LOG2E, acc[g * 4 + 2]);
      acc[g * 4 + 3] = fmaf(b4.w, LOG2E, acc[g * 4 + 3]);
    }
#pragma unroll
    for (int r = 0; r < 16; ++r) {
      acc[r] = __builtin_amdgcn_exp2f(acc[r]);
      lsum += acc[r];
    }
    unsigned c0 = cvt_pk_bf16(acc[0], acc[1]),   c1 = cvt_pk_bf16(acc[2], acc[3]);
    unsigned c2 = cvt_pk_bf16(acc[4], acc[5]),   c3 = cvt_pk_bf16(acc[6], acc[7]);
    unsigned c4 = cvt_pk_bf16(acc[8], acc[9]),   c5 = cvt_pk_bf16(acc[10], acc[11]);
    unsigned c6 = cvt_pk_bf16(acc[12], acc[13]), c7 = cvt_pk_bf16(acc[14], acc[15]);
    pl32swap(c0, c2); pl32swap(c1, c3);
    pl32swap(c4, c6); pl32swap(c5, c7);
    union { unsigned u[4]; bf16x8 v; } a0, a1;
    a0.u[0] = c0; a0.u[1] = c1; a0.u[2] = c2; a0.u[3] = c3;
    a1.u[0] = c4; a1.u[1] = c5; a1.u[2] = c6; a1.u[3] = c7;
#pragma unroll
    for (int dblk = 0; dblk < 2; ++dblk) {
      int rowv = dblk * 32 + lq;
      bf16x8 v0 = *(const bf16x8*)&lV[rowv * 128 + (((kq * 4 + hi) ^ (rowv & 15))) * 8];
      bf16x8 v1 = *(const bf16x8*)&lV[rowv * 128 + (((kq * 4 + 2 + hi) ^ (rowv & 15))) * 8];
      o[dblk] = MFMA32(a0.v, v0, o[dblk]);
      o[dblk] = MFMA32(a1.v, v1, o[dblk]);
    }
    // ---- end compute; drain stage(hp+1), barrier ----
    __builtin_amdgcn_sched_barrier(0);
    asm volatile("s_waitcnt vmcnt(0)" ::: "memory");
    __builtin_amdgcn_sched_barrier(0);
    __builtin_amdgcn_s_barrier();
    __builtin_amdgcn_sched_barrier(0);
  }
#undef STAGE_HP

  // ---- in-block 4-way k-split combine (staging LDS dead) ----
  lsum += __shfl_xor(lsum, 32, 64);
  __syncthreads();
  float* po = (float*)smem;              // 3 parts x 2 strips x 32 q x 64 d
  float* pl = (float*)(smem + 98304);    // 3 x 2 x 32
  if (kq > 0) {
    int part = kq - 1;
#pragma unroll
    for (int r = 0; r < 16; ++r) {
      int qr = (r & 3) + 8 * (r >> 2) + 4 * hi;
      po[((part * 2 + s) * 32 + qr) * 64 + lq] = o[0][r];
      po[((part * 2 + s) * 32 + qr) * 64 + 32 + lq] = o[1][r];
    }
    pl[(part * 2 + s) * 32 + lq] = lsum;
  }
  __syncthreads();
  if (kq == 0) {
    float l = lsum + pl[(0 * 2 + s) * 32 + lq] + pl[(1 * 2 + s) * 32 + lq] +
              pl[(2 * 2 + s) * 32 + lq];
    float linv = 1.0f / l;
#pragma unroll
    for (int r = 0; r < 16; ++r) {
      int qr = (r & 3) + 8 * (r >> 2) + 4 * hi;
      float lr = __shfl(linv, qr, 64);
      float v0 = o[0][r], v1 = o[1][r];
#pragma unroll
      for (int part = 0; part < 3; ++part) {
        v0 += po[((part * 2 + s) * 32 + qr) * 64 + lq];
        v1 += po[((part * 2 + s) * 32 + qr) * 64 + 32 + lq];
      }
      size_t base = ((size_t)b * 2048 + q0 + s * 32 + qr) * 1024 + h * 64 + lq;
      aout[base] = f2bf(v0 * lr);
      aout[base + 32] = f2bf(v1 * lr);
    }
  }
}

extern "C" void kernel_launch(void* const* d_in, const int* in_sizes, int n_in,
                              void* d_out, int out_size, void* d_ws, size_t ws_size,
                              hipStream_t stream) {
  const float* x  = (const float*)d_in[0];
  const float* rb = (const float*)d_in[1];
  const float* Wq = (const float*)d_in[2];
  const float* bq = (const float*)d_in[3];
  const float* Wk = (const float*)d_in[4];
  const float* bk = (const float*)d_in[5];
  const float* Wv = (const float*)d_in[6];
  const float* bv = (const float*)d_in[7];
  const float* Wo = (const float*)d_in[8];
  const float* bo = (const float*)d_in[9];
  float* out = (float*)d_out;
  char* ws = (char*)d_ws;

  u16* xb   = (u16*)(ws);                 // 8 MB  [4096,1024] bf16 (reused as aout)
  u16* W1b  = (u16*)(ws + (8 << 20));     // 6 MB  [3072,1024] bf16 (Wq|Wk|Wv)
  u16* Wob  = (u16*)(ws + (14 << 20));    // 2 MB  [1024,1024] bf16
  u16* qb   = (u16*)(ws + (16 << 20));    // 8 MB  [B,H,L,HD]
  u16* kb2  = (u16*)(ws + (24 << 20));    // 8 MB  [B,H,L,HD]
  u16* vtb  = (u16*)(ws + (32 << 20));    // 8 MB  [B,H,HD,L] (written by QKV GEMM)
  u16* aout = xb;                         // alias: xb dead after QKV GEMM

  cvt_all<<<4096, 256, 0, stream>>>(x, Wq, Wk, Wv, Wo, xb, W1b, Wob);
  gemm_bt<0><<<dim3(24, 32), 256, 0, stream>>>(xb, W1b, qb, kb2, vtb, bq, bk, bv,
                                               nullptr, nullptr);
  attn_kernel<<<1024, 512, 0, stream>>>(qb, kb2, vtb, rb, aout);
  gemm_bt<1><<<dim3(8, 32), 256, 0, stream>>>(aout, Wob, nullptr, nullptr, nullptr,
                                              nullptr, nullptr, nullptr, out, bo);
}

// Round 14
// 163.137 us; speedup vs baseline: 1.3119x; 1.3119x over previous
//
#include <hip/hip_runtime.h>

// MultiheadAttentionWithBias: B=2, L=2048, D=1024, H=16, HD=64
// R14: REQUEST-BYTE DEDUP. R13 counters showed duration independent of
// FETCH (L3-warm replay = same 170us) -> binder is VMEM requested-bytes
// (~27 GB/s/CU at <=16B/lane, hit or miss). Bias was requested TWICE
// (once per batch). Fix: block = 2 batches x 4 q-strips; bias tile staged
// to LDS once per (h,q,k), consumed by both batch-waves. K/V staged for
// both batches. No k-split. Requested: 792 MB -> ~520 MB.

typedef __attribute__((ext_vector_type(8))) short bf16x8;
typedef __attribute__((ext_vector_type(4))) float f32x4;
typedef __attribute__((ext_vector_type(16))) float f32x16;
typedef __attribute__((ext_vector_type(8))) unsigned short u16x8;
using u16 = unsigned short;

#define MFMA16(a, b, c) __builtin_amdgcn_mfma_f32_16x16x32_bf16((a), (b), (c), 0, 0, 0)
#define MFMA32(a, b, c) __builtin_amdgcn_mfma_f32_32x32x16_bf16((a), (b), (c), 0, 0, 0)
#define LOG2E 1.44269504088896f
#define QSCALE (0.125f * 1.44269504088896f)

__device__ __forceinline__ u16 f2bf(float f) {
  union { float f; unsigned int u; } v; v.f = f;
  unsigned int r = v.u + 0x7FFFu + ((v.u >> 16) & 1u);
  return (u16)(r >> 16);
}

__device__ __forceinline__ unsigned cvt_pk_bf16(float lo, float hi) {
  unsigned r;
  asm volatile("v_cvt_pk_bf16_f32 %0, %1, %2" : "=v"(r) : "v"(lo), "v"(hi));
  return r;
}

__device__ __forceinline__ void pl32swap(unsigned& a, unsigned& b) {
#if __has_builtin(__builtin_amdgcn_permlane32_swap)
  typedef unsigned pl2 __attribute__((ext_vector_type(2)));
  pl2 r = __builtin_amdgcn_permlane32_swap(a, b, false, false);
  a = r[0];
  b = r[1];
#else
  asm volatile("v_permlane32_swap_b32 %0, %1" : "+v"(a), "+v"(b));
#endif
}

__device__ __forceinline__ void g2lds16(const void* gsrc, void* ldst) {
  __builtin_amdgcn_global_load_lds(
      (const __attribute__((address_space(1))) unsigned int*)gsrc,
      (__attribute__((address_space(3))) unsigned int*)ldst, 16, 0, 0);
}

// ---------------- merged f32 -> bf16 convert (x, Wq, Wk, Wv, Wo) ----------------
__global__ __launch_bounds__(256) void cvt_all(
    const float* __restrict__ x, const float* __restrict__ wq,
    const float* __restrict__ wk, const float* __restrict__ wv,
    const float* __restrict__ wo, u16* __restrict__ xb,
    u16* __restrict__ w1b, u16* __restrict__ wob) {
  int bid = blockIdx.x, tid = threadIdx.x;
  const float* src; u16* dst; int i;
  if (bid < 2048)      { src = x;  dst = xb;            i = bid * 256 + tid; }
  else if (bid < 2560) { src = wq; dst = w1b;           i = (bid - 2048) * 256 + tid; }
  else if (bid < 3072) { src = wk; dst = w1b + (1<<20); i = (bid - 2560) * 256 + tid; }
  else if (bid < 3584) { src = wv; dst = w1b + (2<<20); i = (bid - 3072) * 256 + tid; }
  else                 { src = wo; dst = wob;           i = (bid - 3584) * 256 + tid; }
  const float4* s = (const float4*)src;
  float4 a = s[2 * i], b = s[2 * i + 1];
  u16x8 o;
  o[0] = f2bf(a.x); o[1] = f2bf(a.y); o[2] = f2bf(a.z); o[3] = f2bf(a.w);
  o[4] = f2bf(b.x); o[5] = f2bf(b.y); o[6] = f2bf(b.z); o[7] = f2bf(b.w);
  ((u16x8*)dst)[i] = o;
}

// ---------------- GEMM C = A * B^T (unchanged, passing) ----------------
template <int MODE>
__global__ __launch_bounds__(256, 2) void gemm_bt(
    const u16* __restrict__ A, const u16* __restrict__ B,
    u16* __restrict__ qp, u16* __restrict__ kp, u16* __restrict__ vp,
    const float* __restrict__ b0, const float* __restrict__ b1,
    const float* __restrict__ b2, float* __restrict__ outp,
    const float* __restrict__ bo) {
  __shared__ __align__(16) u16 lA[128 * 64];
  __shared__ __align__(16) u16 lB[128 * 64];
  const int tid = threadIdx.x;
  const int lane = tid & 63, wid = tid >> 6;
  const int g = lane >> 4, cc = lane & 15;
  const int wr = wid >> 1, wc = wid & 1;
  const int m0 = blockIdx.y * 128, n0 = blockIdx.x * 128;
  f32x4 acc[4][4] = {};
  for (int kt = 0; kt < 16; ++kt) {
    const int kof = kt * 64;
#pragma unroll
    for (int i = 0; i < 4; ++i) {
      int cid = i * 256 + tid;
      int row = cid >> 3;
      int col = (cid & 7) * 8;
      g2lds16(A + (size_t)(m0 + row) * 1024 + kof + col, &lA[(i * 256 + wid * 64) * 8]);
      g2lds16(B + (size_t)(n0 + row) * 1024 + kof + col, &lB[(i * 256 + wid * 64) * 8]);
    }
    __syncthreads();
#pragma unroll
    for (int kc = 0; kc < 2; ++kc) {
      bf16x8 af[4], bfr[4];
#pragma unroll
      for (int mf = 0; mf < 4; ++mf)
        af[mf] = *(const bf16x8*)&lA[(wr * 64 + mf * 16 + cc) * 64 + kc * 32 + g * 8];
#pragma unroll
      for (int nf = 0; nf < 4; ++nf)
        bfr[nf] = *(const bf16x8*)&lB[(wc * 64 + nf * 16 + cc) * 64 + kc * 32 + g * 8];
#pragma unroll
      for (int mf = 0; mf < 4; ++mf)
#pragma unroll
        for (int nf = 0; nf < 4; ++nf)
          acc[mf][nf] = MFMA16(af[mf], bfr[nf], acc[mf][nf]);
    }
    __syncthreads();
  }
#pragma unroll
  for (int mf = 0; mf < 4; ++mf) {
#pragma unroll
    for (int nf = 0; nf < 4; ++nf) {
      int n = n0 + wc * 64 + nf * 16 + cc;
      if (MODE == 0) {
        int which = n >> 10;
        int nn = n & 1023;
        const float* bp = which == 0 ? b0 : (which == 1 ? b1 : b2);
        float bias = bp[nn];
        int h = nn >> 6, hd = nn & 63;
        int mb = m0 + wr * 64 + mf * 16 + g * 4;
        int bb = mb >> 11, ll0 = mb & 2047;
        if (which == 2) {
          ushort4 pk4;
          pk4.x = f2bf(acc[mf][nf][0] + bias);
          pk4.y = f2bf(acc[mf][nf][1] + bias);
          pk4.z = f2bf(acc[mf][nf][2] + bias);
          pk4.w = f2bf(acc[mf][nf][3] + bias);
          *(ushort4*)&vp[(((size_t)(bb * 16 + h)) * 64 + hd) * 2048 + ll0] = pk4;
        } else {
          u16* dp = which == 0 ? qp : kp;
#pragma unroll
          for (int r = 0; r < 4; ++r) {
            float val = acc[mf][nf][r] + bias;
            if (which == 0) val *= QSCALE;
            dp[(((size_t)(bb * 16 + h)) * 2048 + ll0 + r) * 64 + hd] = f2bf(val);
          }
        }
      } else {
        float bias = bo[n];
#pragma unroll
        for (int r = 0; r < 4; ++r) {
          int m = m0 + wr * 64 + mf * 16 + g * 4 + r;
          outp[(size_t)m * 1024 + n] = acc[mf][nf][r] + bias;
        }
      }
    }
  }
}

// ---------------- Flash attention: bias-dedup via batch-merged blocks ----------
// Grid 256 = 16h x 16qb (q-block 128 rows). Block 512 thr = 8 waves =
// 2 batches x 4 q-strips(32 rows). Full k-loop (32 x 64-k tiles), no k-split.
// Per iter staged to dbuf LDS: bias[128q x 64k] f32 32KB (read ONCE from
// global, consumed by BOTH batch-waves), K(b0),K(b1) 8KB each, V^T(b0),V^T(b1)
// 8KB each = 64KB/iter, 128KB LDS total. Fixed-max(-32) softmax in-register
// (R9-R12 refcheck-passed core). XCD swizzle: xcd owns heads 2x,2x+1.
__global__ __launch_bounds__(512, 2) void attn_kernel(
    const u16* __restrict__ qm, const u16* __restrict__ km,
    const u16* __restrict__ vtm, const float* __restrict__ bias,
    u16* __restrict__ aout) {
  __shared__ __align__(16) unsigned char smem[131072];
  // layout: bias dbuf 2x32KB @0; K dbuf 2x16KB @65536; V dbuf 2x16KB @98304
  const int tid = threadIdx.x;
  const int lane = tid & 63, wid = tid >> 6;
  const int lq = lane & 31, hi = lane >> 5;
  const int s = wid & 3, b = wid >> 2;     // q-strip, batch
  // XCD swizzle: 256 blocks; xcd = lin&7 owns heads 2*xcd, 2*xcd+1
  const int lin = blockIdx.x;
  const int xcd = lin & 7, j = lin >> 3;   // j in [0,32)
  const int h = xcd * 2 + (j >> 4);
  const int qb = j & 15;
  const int q0 = qb * 128;
  const u16* kg0 = km + ((size_t)0 * 16 + h) * 2048 * 64;
  const u16* kg1 = km + ((size_t)1 * 16 + h) * 2048 * 64;
  const u16* vg0 = vtm + ((size_t)0 * 16 + h) * 64 * 2048;
  const u16* vg1 = vtm + ((size_t)1 * 16 + h) * 64 * 2048;
  const float* bg = bias + (size_t)h * 2048 * 2048;
  const size_t bh = (size_t)b * 16 + h;
  const u16* qbase = qm + (bh * 2048 + q0 + s * 32) * 64;

  // Q fragments (B-operand), constant: Q[q=lq][d=i*16+8hi..]
  bf16x8 qf[4];
#pragma unroll
  for (int i = 0; i < 4; ++i)
    qf[i] = *(const bf16x8*)&qbase[(size_t)lq * 64 + i * 16 + 8 * hi];

  f32x16 o[2];
#pragma unroll
  for (int r = 0; r < 16; ++r) { o[0][r] = 0.f; o[1][r] = 0.f; }
  float lsum = 0.f;

  // Stage one 64-k panel into buf P: bias 32KB (once!), K/V both batches.
  // All XOR swizzles pre-applied on the SOURCE (T2 both-sides, linear LDS dst).
  // 8 g2lds per thread.
#define STAGE_HP(P, k0n)                                                       \
  {                                                                            \
    unsigned char* bdst = smem + (P) * 32768;                                  \
    unsigned char* kdst = smem + 65536 + (P) * 16384;                          \
    unsigned char* vdst = smem + 98304 + (P) * 16384;                          \
    _Pragma("unroll") for (int i = 0; i < 4; ++i) {                            \
      int slot = i * 512 + tid;                                                \
      int row = slot >> 4, ch = slot & 15;                                     \
      g2lds16(bg + (size_t)(q0 + row) * 2048 + (k0n) + ((ch ^ (row & 15)) << 2), \
              bdst + slot * 16);                                               \
    }                                                                          \
    {                                                                          \
      int kr = tid >> 3, ch = tid & 7;                                         \
      int co = ((ch ^ (kr & 7)) << 3);                                         \
      g2lds16(kg0 + (size_t)((k0n) + kr) * 64 + co, kdst + tid * 16);          \
      g2lds16(kg1 + (size_t)((k0n) + kr) * 64 + co, kdst + 8192 + tid * 16);   \
    }                                                                          \
    {                                                                          \
      int d = tid >> 3, ch = tid & 7;                                          \
      int co = ((ch ^ (d & 7)) << 3);                                          \
      g2lds16(vg0 + (size_t)d * 2048 + (k0n) + co, vdst + tid * 16);           \
      g2lds16(vg1 + (size_t)d * 2048 + (k0n) + co, vdst + 8192 + tid * 16);    \
    }                                                                          \
  }

  // one 32-k subtile: QK^T(-32 acc) + bias(LDS) + exp2 + pack/swap + PV
#define SUBTILE(s_, PP)                                                        \
  {                                                                            \
    const u16* lKp = (const u16*)(smem + 65536 + (PP) * 16384 + b * 8192);     \
    const u16* lVp = (const u16*)(smem + 98304 + (PP) * 16384 + b * 8192);     \
    const float4* lB = (const float4*)(smem + (PP) * 32768);                   \
    f32x16 acc;                                                                \
    _Pragma("unroll") for (int r = 0; r < 16; ++r) acc[r] = -32.0f;            \
    const int krow = (s_) * 32 + lq;                                           \
    _Pragma("unroll") for (int i = 0; i < 4; ++i) {                            \
      bf16x8 kf = *(const bf16x8*)&lKp[krow * 64 + (((2 * i + hi) ^ (krow & 7))) * 8]; \
      acc = MFMA32(kf, qf[i], acc);                                            \
    }                                                                          \
    const int brow = s * 32 + lq;                                              \
    _Pragma("unroll") for (int g = 0; g < 4; ++g) {                            \
      float4 b4 = lB[brow * 16 + (((s_) * 8 + 2 * g + hi) ^ (brow & 15))];     \
      acc[g * 4 + 0] = fmaf(b4.x, LOG2E, acc[g * 4 + 0]);                      \
      acc[g * 4 + 1] = fmaf(b4.y, LOG2E, acc[g * 4 + 1]);                      \
      acc[g * 4 + 2] = fmaf(b4.z, LOG2E, acc[g * 4 + 2]);                      \
      acc[g * 4 + 3] = fmaf(b4.w, LOG2E, acc[g * 4 + 3]);                      \
    }                                                                          \
    _Pragma("unroll") for (int r = 0; r < 16; ++r) {                           \
      acc[r] = __builtin_amdgcn_exp2f(acc[r]);                                 \
      lsum += acc[r];                                                          \
    }                                                                          \
    unsigned c0 = cvt_pk_bf16(acc[0], acc[1]),   c1 = cvt_pk_bf16(acc[2], acc[3]);   \
    unsigned c2 = cvt_pk_bf16(acc[4], acc[5]),   c3 = cvt_pk_bf16(acc[6], acc[7]);   \
    unsigned c4 = cvt_pk_bf16(acc[8], acc[9]),   c5 = cvt_pk_bf16(acc[10], acc[11]); \
    unsigned c6 = cvt_pk_bf16(acc[12], acc[13]), c7 = cvt_pk_bf16(acc[14], acc[15]); \
    pl32swap(c0, c2); pl32swap(c1, c3);                                        \
    pl32swap(c4, c6); pl32swap(c5, c7);                                        \
    union { unsigned u[4]; bf16x8 v; } a0, a1;                                 \
    a0.u[0] = c0; a0.u[1] = c1; a0.u[2] = c2; a0.u[3] = c3;                    \
    a1.u[0] = c4; a1.u[1] = c5; a1.u[2] = c6; a1.u[3] = c7;                    \
    _Pragma("unroll") for (int dblk = 0; dblk < 2; ++dblk) {                   \
      int rowv = dblk * 32 + lq;                                               \
      bf16x8 v0 = *(const bf16x8*)&lVp[rowv * 64 + (((4 * (s_) + hi) ^ (rowv & 7))) * 8];     \
      bf16x8 v1 = *(const bf16x8*)&lVp[rowv * 64 + (((4 * (s_) + 2 + hi) ^ (rowv & 7))) * 8]; \
      o[dblk] = MFMA32(a0.v, v0, o[dblk]);                                     \
      o[dblk] = MFMA32(a1.v, v1, o[dblk]);                                     \
    }                                                                          \
  }

  // prologue: stage k-panel 0 -> buf0
  STAGE_HP(0, 0)
  __builtin_amdgcn_sched_barrier(0);
  asm volatile("s_waitcnt vmcnt(0)" ::: "memory");
  __builtin_amdgcn_sched_barrier(0);
  __builtin_amdgcn_s_barrier();
  __builtin_amdgcn_sched_barrier(0);

#pragma unroll 1
  for (int kt = 0; kt < 32; ++kt) {
    const int P = kt & 1;
    if (kt < 31) { STAGE_HP(P ^ 1, (kt + 1) * 64) }
    __builtin_amdgcn_sched_barrier(0);
    SUBTILE(0, P)
    SUBTILE(1, P)
    __builtin_amdgcn_sched_barrier(0);
    asm volatile("s_waitcnt vmcnt(0)" ::: "memory");
    __builtin_amdgcn_sched_barrier(0);
    __builtin_amdgcn_s_barrier();
    __builtin_amdgcn_sched_barrier(0);
  }
#undef SUBTILE
#undef STAGE_HP

  // epilogue: each wave owns distinct (b, q-strip) -> direct write, no combine
  lsum += __shfl_xor(lsum, 32, 64);
  float linv = 1.0f / lsum;
#pragma unroll
  for (int r = 0; r < 16; ++r) {
    int qr = (r & 3) + 8 * (r >> 2) + 4 * hi;
    float lr = __shfl(linv, qr, 64);
    size_t base = ((size_t)b * 2048 + q0 + s * 32 + qr) * 1024 + h * 64 + lq;
    aout[base] = f2bf(o[0][r] * lr);
    aout[base + 32] = f2bf(o[1][r] * lr);
  }
}

extern "C" void kernel_launch(void* const* d_in, const int* in_sizes, int n_in,
                              void* d_out, int out_size, void* d_ws, size_t ws_size,
                              hipStream_t stream) {
  const float* x  = (const float*)d_in[0];
  const float* rb = (const float*)d_in[1];
  const float* Wq = (const float*)d_in[2];
  const float* bq = (const float*)d_in[3];
  const float* Wk = (const float*)d_in[4];
  const float* bk = (const float*)d_in[5];
  const float* Wv = (const float*)d_in[6];
  const float* bv = (const float*)d_in[7];
  const float* Wo = (const float*)d_in[8];
  const float* bo = (const float*)d_in[9];
  float* out = (float*)d_out;
  char* ws = (char*)d_ws;

  u16* xb   = (u16*)(ws);                 // 8 MB  [4096,1024] bf16 (reused as aout)
  u16* W1b  = (u16*)(ws + (8 << 20));     // 6 MB  [3072,1024] bf16 (Wq|Wk|Wv)
  u16* Wob  = (u16*)(ws + (14 << 20));    // 2 MB  [1024,1024] bf16
  u16* qb   = (u16*)(ws + (16 << 20));    // 8 MB  [B,H,L,HD]
  u16* kb2  = (u16*)(ws + (24 << 20));    // 8 MB  [B,H,L,HD]
  u16* vtb  = (u16*)(ws + (32 << 20));    // 8 MB  [B,H,HD,L] (written by QKV GEMM)
  u16* aout = xb;                         // alias: xb dead after QKV GEMM

  cvt_all<<<4096, 256, 0, stream>>>(x, Wq, Wk, Wv, Wo, xb, W1b, Wob);
  gemm_bt<0><<<dim3(24, 32), 256, 0, stream>>>(xb, W1b, qb, kb2, vtb, bq, bk, bv,
                                               nullptr, nullptr);
  attn_kernel<<<256, 512, 0, stream>>>(qb, kb2, vtb, rb, aout);
  gemm_bt<1><<<dim3(8, 32), 256, 0, stream>>>(aout, Wob, nullptr, nullptr, nullptr,
                                              nullptr, nullptr, nullptr, out, bo);
}